// Round 2
// baseline (9412.772 us; speedup 1.0000x reference)
//
#include <hip/hip_runtime.h>

#define SEQ   2048
#define BATCH 128
#define INDIM 128
#define HID   256
#define BH    (BATCH * HID)

// Fully fused CTRNN: one block per batch element, 256 threads (one per hidden
// unit). Thread j holds W_in[j,:] and W_h[j,:] in registers (~405 VGPRs -> 1
// block/CU). h and x_t live in LDS (16B-aligned; broadcast float4 reads).
// d_out is WRITE-ONLY (no in-place aliasing anywhere).
__global__ __launch_bounds__(256, 1) void ctrnn_fused(
    const float* __restrict__ x, const float* __restrict__ h0,
    const float* __restrict__ W_in, const float* __restrict__ b_in,
    const float* __restrict__ W_h, const float* __restrict__ b_h,
    float* __restrict__ out) {
  __shared__ __align__(16) float hs[HID];
  __shared__ __align__(16) float xs[INDIM];

  const int b = blockIdx.x;
  const int j = threadIdx.x;

  // --- load weights into registers ---
  float win[INDIM];
#pragma unroll
  for (int k4 = 0; k4 < INDIM / 4; ++k4) {
    float4 v = ((const float4*)(W_in + (size_t)j * INDIM))[k4];
    win[4 * k4 + 0] = v.x; win[4 * k4 + 1] = v.y;
    win[4 * k4 + 2] = v.z; win[4 * k4 + 3] = v.w;
  }
  float wh[HID];
#pragma unroll
  for (int k4 = 0; k4 < HID / 4; ++k4) {
    float4 v = ((const float4*)(W_h + (size_t)j * HID))[k4];
    wh[4 * k4 + 0] = v.x; wh[4 * k4 + 1] = v.y;
    wh[4 * k4 + 2] = v.z; wh[4 * k4 + 3] = v.w;
  }
  const float bias = b_in[j] + b_h[j];

  const size_t idx = (size_t)b * HID + j;
  float hj = h0[idx];

  // x[t,b,:] base for this block, as float4; stride between timesteps
  const float4* xg = (const float4*)(x + (size_t)b * INDIM);
  const int xstride4 = BATCH * INDIM / 4;

  // prefetch x[0,b,:] (threads 0..31 each hold one float4)
  float4 xr = make_float4(0.f, 0.f, 0.f, 0.f);
  if (j < INDIM / 4) xr = xg[j];

  for (int t = 0; t < SEQ; ++t) {
    // publish current h and current x_t to LDS
    if (j < INDIM / 4) ((float4*)xs)[j] = xr;
    hs[j] = hj;
    __syncthreads();

    // prefetch next timestep's x early (latency hidden by the dot products)
    if (j < INDIM / 4 && t + 1 < SEQ) xr = xg[(size_t)(t + 1) * xstride4 + j];

    float a0 = 0.f, a1 = 0.f, a2 = 0.f, a3 = 0.f;
#pragma unroll
    for (int k4 = 0; k4 < INDIM / 4; ++k4) {
      float4 v = ((const float4*)xs)[k4];
      a0 = fmaf(win[4 * k4 + 0], v.x, a0);
      a1 = fmaf(win[4 * k4 + 1], v.y, a1);
      a2 = fmaf(win[4 * k4 + 2], v.z, a2);
      a3 = fmaf(win[4 * k4 + 3], v.w, a3);
    }
#pragma unroll
    for (int k4 = 0; k4 < HID / 4; ++k4) {
      float4 v = ((const float4*)hs)[k4];
      a0 = fmaf(wh[4 * k4 + 0], v.x, a0);
      a1 = fmaf(wh[4 * k4 + 1], v.y, a1);
      a2 = fmaf(wh[4 * k4 + 2], v.z, a2);
      a3 = fmaf(wh[4 * k4 + 3], v.w, a3);
    }
    const float pre = ((a0 + a1) + (a2 + a3)) + bias;
    const float hn = fmaxf(pre, 0.f);
    hj = 0.9f * hj + 0.1f * hn;
    out[(size_t)t * BH + idx] = hj;

    __syncthreads();  // protect hs/xs from next iteration's overwrite
  }

  // h_final, appended after outputs
  out[(size_t)SEQ * BH + idx] = hj;
}

extern "C" void kernel_launch(void* const* d_in, const int* in_sizes, int n_in,
                              void* d_out, int out_size, void* d_ws, size_t ws_size,
                              hipStream_t stream) {
  const float* x    = (const float*)d_in[0];
  const float* h0   = (const float*)d_in[1];
  const float* W_in = (const float*)d_in[2];
  const float* b_in = (const float*)d_in[3];
  const float* W_h  = (const float*)d_in[4];
  const float* b_h  = (const float*)d_in[5];
  float* out = (float*)d_out;

  ctrnn_fused<<<BATCH, 256, 0, stream>>>(x, h0, W_in, b_in, W_h, b_h, out);
}